// Round 1
// baseline (12070.170 us; speedup 1.0000x reference)
//
#include <hip/hip_runtime.h>

// ============================================================================
// 2-layer dynamic-quantized LSTM, T=1024, B=16, I=H=1024.
//
// Design:
//  - Phase A (parallel): quantize weights (int8, per-tensor scale) and x
//    (int8, per-timestep scale) exactly as the reference (IEEE div + rintf).
//  - Phase B: ONE persistent kernel, 128 blocks x 256 threads, custom
//    device-scope grid barrier. Layer-pipelined wavefront: at step s,
//    blocks 0..63 run layer0 t=s, blocks 64..127 run layer1 t=s-1.
//    Each block owns 16 hidden units; wave g (0..3) computes gate g's
//    16x16 output tile via v_mfma_i32_16x16x64_i8 with its int8 weight
//    fragments held in VGPRs for the entire kernel (no weight traffic).
//    c-state lives in one register per thread. h is broadcast through
//    global memory (double-buffered), made coherent by the barrier's
//    agent-scope release/acquire fences.
//
// Workspace layout (needs ~34.6 MB):
//   [0,64)        u32 wmax[4]              (abs-max bits of the 4 weight tensors)
//   [64,72)       u32 bar[2]               (barrier counter, generation)
//   [1024,5120)   f32 xscale[1024]
//   [8192,16384)  u32 hmax0[..]            (abs-max of layer0 h entering step t)
//   [16384,24576) u32 hmax1[..]
//   [64K,192K)    f32 h0buf[2][16][1024]
//   [192K,320K)   f32 h1buf[2][16][1024]
//   [1M,17M)      i8  wq[4][4096][1024]    (ih0, hh0, ih1, hh1)
//   [17M,33M+1M)  i8  xq[1024][16][1024]
// ============================================================================

#define T_STEPS 1024
#define NBLK 128

typedef int v4i __attribute__((ext_vector_type(4)));

#define DEV static __device__ __forceinline__

DEV float qclip(float v) { return fminf(fmaxf(v, -127.0f), 127.0f); }

DEV unsigned pack4i(float a, float b, float c, float d) {
  int ia = (int)a, ib = (int)b, ic = (int)c, id = (int)d;
  return (unsigned)(ia & 0xff) | ((unsigned)(ib & 0xff) << 8) |
         ((unsigned)(ic & 0xff) << 16) | ((unsigned)(id & 0xff) << 24);
}

// one-time quantization: true IEEE division to match reference x / s exactly
DEV float qdiv(float v, float s) { return qclip(rintf(v / s)); }
// hot-loop quantization: multiply by reciprocal (<=1ulp vs reference)
DEV float qmul(float v, float inv) { return qclip(rintf(v * inv)); }

// ---------------------------------------------------------------------------
__global__ void init_kernel(const float* __restrict__ h0in,
                            float* __restrict__ h0buf, float* __restrict__ h1buf,
                            unsigned* hmax0, unsigned* hmax1) {
  const int layer = blockIdx.x;
  const int tid = threadIdx.x;
  const float* src = h0in + layer * 16384;
  // layer0's first read is slot 1 (step 0); layer1's first read is slot 0 (step 1)
  float* dst = layer ? h1buf : (h0buf + 16384);
  __shared__ float red[256];
  float m = 0.0f;
  for (int i = tid; i < 16384; i += 256) {
    float v = src[i];
    dst[i] = v;
    m = fmaxf(m, fabsf(v));
  }
  red[tid] = m;
  __syncthreads();
  for (int off = 128; off > 0; off >>= 1) {
    if (tid < off) red[tid] = fmaxf(red[tid], red[tid + off]);
    __syncthreads();
  }
  if (tid == 0) (layer ? hmax1 : hmax0)[0] = __float_as_uint(red[0]);
}

// ---------------------------------------------------------------------------
__global__ void wabsmax_kernel(const float* __restrict__ w0, const float* __restrict__ w1,
                               const float* __restrict__ w2, const float* __restrict__ w3,
                               unsigned* wmax) {
  const int tensor = blockIdx.x >> 8;   // 256 blocks / tensor
  const int blk = blockIdx.x & 255;
  const float* w = tensor == 0 ? w0 : tensor == 1 ? w1 : tensor == 2 ? w2 : w3;
  const int tid = threadIdx.x;
  const float4* src = (const float4*)w;
  float m = 0.0f;
#pragma unroll
  for (int i = 0; i < 16; ++i) {
    float4 v = src[blk * 4096 + (i << 8) + tid];
    m = fmaxf(m, fmaxf(fmaxf(fabsf(v.x), fabsf(v.y)), fmaxf(fabsf(v.z), fabsf(v.w))));
  }
  __shared__ float red[256];
  red[tid] = m;
  __syncthreads();
  for (int off = 128; off > 0; off >>= 1) {
    if (tid < off) red[tid] = fmaxf(red[tid], red[tid + off]);
    __syncthreads();
  }
  if (tid == 0)
    __hip_atomic_fetch_max(&wmax[tensor], __float_as_uint(red[0]),
                           __ATOMIC_RELAXED, __HIP_MEMORY_SCOPE_AGENT);
}

// ---------------------------------------------------------------------------
__global__ void wquant_kernel(const float* __restrict__ w0, const float* __restrict__ w1,
                              const float* __restrict__ w2, const float* __restrict__ w3,
                              const unsigned* __restrict__ wmax,
                              unsigned char* __restrict__ wq) {
  const int tensor = blockIdx.x >> 12;  // 4096 blocks / tensor
  const int blk = blockIdx.x & 4095;
  const float* w = tensor == 0 ? w0 : tensor == 1 ? w1 : tensor == 2 ? w2 : w3;
  const float s = fmaxf(__uint_as_float(wmax[tensor]), 1e-8f) / 127.0f;
  const int f4 = (blk << 8) + threadIdx.x;
  float4 v = ((const float4*)w)[f4];
  unsigned* dst = (unsigned*)(wq + (size_t)tensor * 4194304u);
  dst[f4] = pack4i(qdiv(v.x, s), qdiv(v.y, s), qdiv(v.z, s), qdiv(v.w, s));
}

// ---------------------------------------------------------------------------
__global__ void xquant_kernel(const float* __restrict__ x, float* __restrict__ xscale,
                              unsigned char* __restrict__ xq) {
  const int t = blockIdx.x;
  const int tid = threadIdx.x;
  const float4* src = (const float4*)(x + (size_t)t * 16384u);
  float4 vb[16];
  float m = 0.0f;
#pragma unroll
  for (int i = 0; i < 16; ++i) {
    float4 v = src[(i << 8) + tid];
    vb[i] = v;
    m = fmaxf(m, fmaxf(fmaxf(fabsf(v.x), fabsf(v.y)), fmaxf(fabsf(v.z), fabsf(v.w))));
  }
  __shared__ float red[256];
  red[tid] = m;
  __syncthreads();
  for (int off = 128; off > 0; off >>= 1) {
    if (tid < off) red[tid] = fmaxf(red[tid], red[tid + off]);
    __syncthreads();
  }
  __shared__ float ssh;
  if (tid == 0) {
    float s = fmaxf(red[0], 1e-8f) / 127.0f;
    xscale[t] = s;
    ssh = s;
  }
  __syncthreads();
  const float s = ssh;
  unsigned* dst = (unsigned*)(xq + (size_t)t * 16384u);
#pragma unroll
  for (int i = 0; i < 16; ++i) {
    float4 v = vb[i];
    dst[(i << 8) + tid] = pack4i(qdiv(v.x, s), qdiv(v.y, s), qdiv(v.z, s), qdiv(v.w, s));
  }
}

// ---------------------------------------------------------------------------
// Persistent sequential kernel.
__global__ __launch_bounds__(256, 1) void seq_kernel(
    const unsigned char* __restrict__ xq, const float* __restrict__ xscale,
    const unsigned char* __restrict__ wq_base, const unsigned* __restrict__ wmax,
    const float* __restrict__ bih0, const float* __restrict__ bhh0,
    const float* __restrict__ bih1, const float* __restrict__ bhh1,
    float* __restrict__ h0buf, float* __restrict__ h1buf,
    unsigned* __restrict__ hmax0, unsigned* __restrict__ hmax1,
    unsigned* bar, const float* __restrict__ c0in, float* __restrict__ dout) {
  const int wg = blockIdx.x;
  const int layer = wg >> 6;           // 0..63 -> layer0, 64..127 -> layer1
  const int j0 = (wg & 63) << 4;       // 16 hidden units per block
  const int tid = threadIdx.x;
  const int g = tid >> 6;              // wave id == gate id (i,f,g,o)
  const int lane = tid & 63;

  __shared__ __align__(16) unsigned char axq[16][1040];  // x operand, int8 (+16B row pad)
  __shared__ __align__(16) unsigned char ahq[16][1040];  // h operand, int8
  __shared__ float gl[4][16][16];                        // activated gates
  __shared__ float red[256];

  const unsigned char* wqi = wq_base + (size_t)(2 * layer) * 4194304u;
  const unsigned char* wqh = wq_base + (size_t)(2 * layer + 1) * 4194304u;
  const float* bih = layer ? bih1 : bih0;
  const float* bhh = layer ? bhh1 : bhh0;
  float* myh = layer ? h1buf : h0buf;
  unsigned* myhmax = layer ? hmax1 : hmax0;

  const float s_wi = fmaxf(__uint_as_float(wmax[2 * layer + 0]), 1e-8f) / 127.0f;
  const float s_wh = fmaxf(__uint_as_float(wmax[2 * layer + 1]), 1e-8f) / 127.0f;

  // MFMA 16x16x64 i8 operand mapping (derived from verified bf16 16x16x32):
  //   A: row = lane&15, k = (lane>>4)*16 + j (j=0..15, contiguous bytes)
  //   B: col = lane&15, same k mapping
  //   D: col = lane&15, row = (lane>>4)*4 + r
  const int ncol = (g << 10) + j0 + (lane & 15);  // global gate column 0..4095
  const int ksub = (lane >> 4) << 4;
  const int arow = lane & 15;

  // Preload this wave's weight fragments into registers (held for all steps).
  v4i wfi[16], wfh[16];
  {
    const unsigned char* pi = wqi + (size_t)ncol * 1024u + ksub;
    const unsigned char* ph = wqh + (size_t)ncol * 1024u + ksub;
#pragma unroll
    for (int kk = 0; kk < 16; ++kk) {
      wfi[kk] = *(const v4i*)(pi + (kk << 6));
      wfh[kk] = *(const v4i*)(ph + (kk << 6));
    }
  }
  const float bsum = bih[ncol] + bhh[ncol];

  // cell state: one (b, j) pair per thread, in a register for the whole kernel
  const int cb = tid >> 4, cj = tid & 15;
  float creg = c0in[layer * 16384 + cb * 1024 + j0 + cj];

  for (int s = 0; s <= T_STEPS; ++s) {
    const bool active = (layer == 0) ? (s < T_STEPS) : (s >= 1);
    if (active) {
      const int t = (layer == 0) ? s : (s - 1);
      const int rslot = (s - 1) & 1;
      float sx, sh;

      // ---- stage x operand into LDS (int8) ----
      if (layer == 0) {
        sx = xscale[t];
        const v4i* src = (const v4i*)(xq + (size_t)t * 16384u);
#pragma unroll
        for (int i = 0; i < 4; ++i) {
          int idx = (i << 8) + tid;
          v4i v = src[idx];
          int e = idx << 4;
          *(v4i*)&axq[e >> 10][e & 1023] = v;
        }
      } else {
        // layer1 x-input = layer0's h at time t (written last step), scale = its absmax
        float am = __uint_as_float(hmax0[t + 1]);
        sx = fmaxf(am, 1e-8f) / 127.0f;
        float inv = 1.0f / sx;
        const float4* src = (const float4*)(h0buf + rslot * 16384);
#pragma unroll
        for (int i = 0; i < 16; ++i) {
          int f4 = (i << 8) + tid;
          float4 v = src[f4];
          unsigned u = pack4i(qmul(v.x, inv), qmul(v.y, inv), qmul(v.z, inv), qmul(v.w, inv));
          int e = f4 << 2;
          *(unsigned*)&axq[e >> 10][e & 1023] = u;
        }
      }
      // ---- stage h operand into LDS (int8) ----
      {
        float am = __uint_as_float(myhmax[t]);
        sh = fmaxf(am, 1e-8f) / 127.0f;
        float inv = 1.0f / sh;
        const float4* src = (const float4*)(myh + rslot * 16384);
#pragma unroll
        for (int i = 0; i < 16; ++i) {
          int f4 = (i << 8) + tid;
          float4 v = src[f4];
          unsigned u = pack4i(qmul(v.x, inv), qmul(v.y, inv), qmul(v.z, inv), qmul(v.w, inv));
          int e = f4 << 2;
          *(unsigned*)&ahq[e >> 10][e & 1023] = u;
        }
      }
      __syncthreads();

      // ---- MFMA: exact integer matmuls ----
      v4i accx = {0, 0, 0, 0}, acch = {0, 0, 0, 0};
#pragma unroll
      for (int kk = 0; kk < 16; ++kk) {
        v4i a = *(const v4i*)&axq[arow][(kk << 6) + ksub];
        accx = __builtin_amdgcn_mfma_i32_16x16x64_i8(a, wfi[kk], accx, 0, 0, 0);
      }
#pragma unroll
      for (int kk = 0; kk < 16; ++kk) {
        v4i a = *(const v4i*)&ahq[arow][(kk << 6) + ksub];
        acch = __builtin_amdgcn_mfma_i32_16x16x64_i8(a, wfh[kk], acch, 0, 0, 0);
      }

      // ---- epilogue: scales + biases + nonlinearity, per wave = per gate ----
      const float fx = sx * s_wi, fh = sh * s_wh;
#pragma unroll
      for (int r = 0; r < 4; ++r) {
        float gate = (float)accx[r] * fx + (float)acch[r] * fh + bsum;
        float act = (g == 2) ? tanhf(gate) : 1.0f / (1.0f + expf(-gate));
        gl[g][((lane >> 4) << 2) + r][lane & 15] = act;
      }
      __syncthreads();

      // ---- LSTM cell (one element per thread) ----
      float gi = gl[0][cb][cj], gf = gl[1][cb][cj];
      float gg = gl[2][cb][cj], go = gl[3][cb][cj];
      float cnew = gf * creg + gi * gg;
      creg = cnew;
      float h = go * tanhf(cnew);
      const int wslot = s & 1;
      myh[wslot * 16384 + cb * 1024 + j0 + cj] = h;
      if (layer == 1) dout[(size_t)t * 16384u + cb * 1024 + j0 + cj] = h;
      if (t == T_STEPS - 1) dout[16777216u + layer * 16384 + cb * 1024 + j0 + cj] = h;

      // block absmax of h chunk -> global atomic max (entering-scale for t+1)
      red[tid] = fabsf(h);
      __syncthreads();
      for (int off = 128; off > 0; off >>= 1) {
        if (tid < off) red[tid] = fmaxf(red[tid], red[tid + off]);
        __syncthreads();
      }
      if (tid == 0)
        __hip_atomic_fetch_max(&myhmax[t + 1], __float_as_uint(red[0]),
                               __ATOMIC_RELAXED, __HIP_MEMORY_SCOPE_AGENT);
    }

    // ---- grid barrier (agent-scope release/acquire for cross-XCD coherence) ----
    __syncthreads();  // drains each wave's vmem (compiler emits vmcnt(0))
    if (tid == 0) {
      __builtin_amdgcn_fence(__ATOMIC_RELEASE, "agent");  // L2 writeback
      unsigned gsn = __hip_atomic_load(&bar[1], __ATOMIC_RELAXED, __HIP_MEMORY_SCOPE_AGENT);
      unsigned a = __hip_atomic_fetch_add(&bar[0], 1u, __ATOMIC_RELAXED, __HIP_MEMORY_SCOPE_AGENT);
      if (a == NBLK - 1u) {
        __hip_atomic_store(&bar[0], 0u, __ATOMIC_RELAXED, __HIP_MEMORY_SCOPE_AGENT);
        __hip_atomic_store(&bar[1], gsn + 1u, __ATOMIC_RELEASE, __HIP_MEMORY_SCOPE_AGENT);
      } else {
        int guard = 0;
        while (__hip_atomic_load(&bar[1], __ATOMIC_RELAXED, __HIP_MEMORY_SCOPE_AGENT) == gsn &&
               guard < (1 << 22)) {
          __builtin_amdgcn_s_sleep(1);
          ++guard;
        }
      }
      __builtin_amdgcn_fence(__ATOMIC_ACQUIRE, "agent");  // L1/L2 invalidate
    }
    __syncthreads();
  }

  // final cell state -> c_n
  dout[16777216u + 32768u + layer * 16384 + cb * 1024 + j0 + cj] = creg;
}

// ---------------------------------------------------------------------------
extern "C" void kernel_launch(void* const* d_in, const int* in_sizes, int n_in,
                              void* d_out, int out_size, void* d_ws, size_t ws_size,
                              hipStream_t stream) {
  (void)in_sizes; (void)n_in; (void)out_size; (void)ws_size;
  const float* x     = (const float*)d_in[0];
  const float* h0in  = (const float*)d_in[1];
  const float* c0in  = (const float*)d_in[2];
  const float* w_ih0 = (const float*)d_in[3];
  const float* w_hh0 = (const float*)d_in[4];
  const float* b_ih0 = (const float*)d_in[5];
  const float* b_hh0 = (const float*)d_in[6];
  const float* w_ih1 = (const float*)d_in[7];
  const float* w_hh1 = (const float*)d_in[8];
  const float* b_ih1 = (const float*)d_in[9];
  const float* b_hh1 = (const float*)d_in[10];

  char* ws = (char*)d_ws;
  unsigned* wmax   = (unsigned*)(ws + 0);
  unsigned* bar    = (unsigned*)(ws + 64);
  float* xscale    = (float*)(ws + 1024);
  unsigned* hmax0  = (unsigned*)(ws + 8192);
  unsigned* hmax1  = (unsigned*)(ws + 16384);
  float* h0buf     = (float*)(ws + 65536);
  float* h1buf     = (float*)(ws + 65536 + 131072);
  unsigned char* wqb = (unsigned char*)(ws + (1u << 20));
  unsigned char* xq  = (unsigned char*)(ws + (1u << 20) + 4u * 4194304u);

  hipMemsetAsync(ws, 0, 65536, stream);
  hipLaunchKernelGGL(init_kernel, dim3(2), dim3(256), 0, stream,
                     h0in, h0buf, h1buf, hmax0, hmax1);
  hipLaunchKernelGGL(wabsmax_kernel, dim3(1024), dim3(256), 0, stream,
                     w_ih0, w_hh0, w_ih1, w_hh1, wmax);
  hipLaunchKernelGGL(wquant_kernel, dim3(16384), dim3(256), 0, stream,
                     w_ih0, w_hh0, w_ih1, w_hh1, wmax, wqb);
  hipLaunchKernelGGL(xquant_kernel, dim3(1024), dim3(256), 0, stream,
                     x, xscale, xq);
  hipLaunchKernelGGL(seq_kernel, dim3(NBLK), dim3(256), 0, stream,
                     xq, xscale, wqb, wmax,
                     b_ih0, b_hh0, b_ih1, b_hh1,
                     h0buf, h1buf, hmax0, hmax1,
                     bar, c0in, (float*)d_out);
}

// Round 2
// 5539.693 us; speedup vs baseline: 2.1789x; 2.1789x over previous
//
#include <hip/hip_runtime.h>

// ============================================================================
// 2-layer dynamic-quantized LSTM, T=1024, B=16, I=H=1024.
//
// Round-2 design (fence-free, layer-decoupled):
//  - Phase A unchanged: exact reference quantization of weights and x.
//  - ONE persistent kernel, 64 blocks x 512 threads (32 blocks/layer,
//    8 waves/block, 32 hidden units/block, weights in VGPRs for all steps).
//  - NO cache-wide fences. Cross-block data (h rings, h0q ring, hmax, flags)
//    uses per-access coherent ops: global_load/store with sc0 sc1 (bypass
//    L1/L2, LLC is the coherence point) or relaxed agent-scope atomics.
//    Ordering: s_waitcnt vmcnt(0) (per wave) + __syncthreads before the
//    arrival-flag store. xq/weights/biases stay plain-cached (L2-resident,
//    never invalidated).
//  - Per-layer barrier: flags[b] = completed-step count (monotonic, no reset,
//    no ABA). A waiting block's wave0 scans all 32 flags with one lane-
//    parallel coherent load + __ballot. No counter RMW chain, no releaser.
//  - Layer decoupling: layer0 publishes h0(t) BOTH as f32 (own recurrence,
//    2-slot ring) and as producer-quantized int8 h0q (8-slot ring, written
//    during step t+1 when hmax0[t+1] is final). Layer1 step u waits
//    flags0 >= u+2, reads 16KB int8 directly. Layer0 ring-guard: step s
//    waits flags1 >= s-8. Static/x-side work is hoisted BEFORE the
//    recurrence wait to overlap barrier latency.
//
// Workspace (~34 MB):
//   [0,64)       u32 wmax[4]
//   [128,256)    u32 flags0[32]      [256,384) u32 flags1[32]
//   [1024,5120)  f32 xscale[1024]
//   [8192,...)   u32 hmax0[1026]     [16384,...) u32 hmax1[1026]
//   [64K,192K)   f32 h0f[2][16384]   [192K,320K) f32 h1f[2][16384]
//   [320K,448K)  i8  h0q[8][16384]
//   [1M,17M)     i8  wq[4][4096][1024]
//   [17M,33M)    i8  xq[1024][16][1024]
// ============================================================================

#define T_STEPS 1024

typedef int v4i __attribute__((ext_vector_type(4)));
typedef float v4f __attribute__((ext_vector_type(4)));

#define DEV static __device__ __forceinline__

DEV float qclip(float v) { return fminf(fmaxf(v, -127.0f), 127.0f); }

DEV unsigned pack4i(float a, float b, float c, float d) {
  int ia = (int)a, ib = (int)b, ic = (int)c, id = (int)d;
  return (unsigned)(ia & 0xff) | ((unsigned)(ib & 0xff) << 8) |
         ((unsigned)(ic & 0xff) << 16) | ((unsigned)(id & 0xff) << 24);
}

DEV float qdiv(float v, float s) { return qclip(rintf(v / s)); }        // one-time
DEV float qmul(float v, float inv) { return qclip(rintf(v * inv)); }    // hot loop

// ---- coherent (LLC-visible) memory ops: bypass non-coherent L1/L2 ----------
DEV v4i cloadi(const void* p) {
  v4i r;
  asm volatile("global_load_dwordx4 %0, %1, off sc0 sc1" : "=v"(r) : "v"(p) : "memory");
  return r;
}
DEV v4f cloadf(const void* p) {
  v4f r;
  asm volatile("global_load_dwordx4 %0, %1, off sc0 sc1" : "=v"(r) : "v"(p) : "memory");
  return r;
}
DEV void cstore16(void* p, v4f v) {
  asm volatile("global_store_dwordx4 %0, %1, off sc0 sc1" :: "v"(p), "v"(v) : "memory");
}
DEV void cstore4(void* p, unsigned v) {
  asm volatile("global_store_dword %0, %1, off sc0 sc1" :: "v"(p), "v"(v) : "memory");
}
DEV void vdone() {  // drain this wave's vmem (loads AND coherent stores)
  asm volatile("s_waitcnt vmcnt(0)" ::: "memory");
  __builtin_amdgcn_sched_barrier(0);
}

DEV unsigned aload(const unsigned* p) {
  return __hip_atomic_load((unsigned*)p, __ATOMIC_RELAXED, __HIP_MEMORY_SCOPE_AGENT);
}
DEV void astore(unsigned* p, unsigned v) {
  __hip_atomic_store(p, v, __ATOMIC_RELAXED, __HIP_MEMORY_SCOPE_AGENT);
}
DEV void amax(unsigned* p, unsigned v) {
  __hip_atomic_fetch_max(p, v, __ATOMIC_RELAXED, __HIP_MEMORY_SCOPE_AGENT);
}

// Distributed barrier wait: wave0 lanes 0..31 scan fa[lane] >= ta,
// lanes 32..63 scan fb[lane-32] >= tb (or pass if fb == nullptr).
DEV void wait2(const unsigned* fa, unsigned ta, const unsigned* fb, unsigned tb, int tid) {
  if (tid < 64) {
    const unsigned* p = (tid < 32) ? (fa + tid) : (fb ? fb + (tid - 32) : fa + (tid - 32));
    const unsigned tgt = (tid < 32) ? ta : (fb ? tb : 0u);
    unsigned guard = 0;
    for (;;) {
      unsigned v = aload(p);
      if (__ballot(v >= tgt) == ~0ull) break;
      __builtin_amdgcn_s_sleep(1);
      if (++guard > (1u << 18)) break;  // fail visibly, don't hang
    }
  }
  __syncthreads();
}

// ---------------------------------------------------------------------------
__global__ void init_kernel(const float* __restrict__ h0in,
                            float* __restrict__ h0f, float* __restrict__ h1f,
                            unsigned* hmax0, unsigned* hmax1) {
  const int layer = blockIdx.x;
  const int tid = threadIdx.x;
  const float* src = h0in + layer * 16384;
  float* dst = (layer ? h1f : h0f) + 16384;  // both layers first read slot 1
  __shared__ float red[256];
  float m = 0.0f;
  for (int i = tid; i < 16384; i += 256) {
    float v = src[i];
    dst[i] = v;
    m = fmaxf(m, fabsf(v));
  }
  red[tid] = m;
  __syncthreads();
  for (int off = 128; off > 0; off >>= 1) {
    if (tid < off) red[tid] = fmaxf(red[tid], red[tid + off]);
    __syncthreads();
  }
  if (tid == 0) (layer ? hmax1 : hmax0)[0] = __float_as_uint(red[0]);
}

// ---------------------------------------------------------------------------
__global__ void wabsmax_kernel(const float* __restrict__ w0, const float* __restrict__ w1,
                               const float* __restrict__ w2, const float* __restrict__ w3,
                               unsigned* wmax) {
  const int tensor = blockIdx.x >> 8;
  const int blk = blockIdx.x & 255;
  const float* w = tensor == 0 ? w0 : tensor == 1 ? w1 : tensor == 2 ? w2 : w3;
  const int tid = threadIdx.x;
  const float4* src = (const float4*)w;
  float m = 0.0f;
#pragma unroll
  for (int i = 0; i < 16; ++i) {
    float4 v = src[blk * 4096 + (i << 8) + tid];
    m = fmaxf(m, fmaxf(fmaxf(fabsf(v.x), fabsf(v.y)), fmaxf(fabsf(v.z), fabsf(v.w))));
  }
  __shared__ float red[256];
  red[tid] = m;
  __syncthreads();
  for (int off = 128; off > 0; off >>= 1) {
    if (tid < off) red[tid] = fmaxf(red[tid], red[tid + off]);
    __syncthreads();
  }
  if (tid == 0)
    __hip_atomic_fetch_max(&wmax[tensor], __float_as_uint(red[0]),
                           __ATOMIC_RELAXED, __HIP_MEMORY_SCOPE_AGENT);
}

// ---------------------------------------------------------------------------
__global__ void wquant_kernel(const float* __restrict__ w0, const float* __restrict__ w1,
                              const float* __restrict__ w2, const float* __restrict__ w3,
                              const unsigned* __restrict__ wmax,
                              unsigned char* __restrict__ wq) {
  const int tensor = blockIdx.x >> 12;
  const int blk = blockIdx.x & 4095;
  const float* w = tensor == 0 ? w0 : tensor == 1 ? w1 : tensor == 2 ? w2 : w3;
  const float s = fmaxf(__uint_as_float(wmax[tensor]), 1e-8f) / 127.0f;
  const int f4 = (blk << 8) + threadIdx.x;
  float4 v = ((const float4*)w)[f4];
  unsigned* dst = (unsigned*)(wq + (size_t)tensor * 4194304u);
  dst[f4] = pack4i(qdiv(v.x, s), qdiv(v.y, s), qdiv(v.z, s), qdiv(v.w, s));
}

// ---------------------------------------------------------------------------
__global__ void xquant_kernel(const float* __restrict__ x, float* __restrict__ xscale,
                              unsigned char* __restrict__ xq) {
  const int t = blockIdx.x;
  const int tid = threadIdx.x;
  const float4* src = (const float4*)(x + (size_t)t * 16384u);
  float4 vb[16];
  float m = 0.0f;
#pragma unroll
  for (int i = 0; i < 16; ++i) {
    float4 v = src[(i << 8) + tid];
    vb[i] = v;
    m = fmaxf(m, fmaxf(fmaxf(fabsf(v.x), fabsf(v.y)), fmaxf(fabsf(v.z), fabsf(v.w))));
  }
  __shared__ float red[256];
  red[tid] = m;
  __syncthreads();
  for (int off = 128; off > 0; off >>= 1) {
    if (tid < off) red[tid] = fmaxf(red[tid], red[tid + off]);
    __syncthreads();
  }
  __shared__ float ssh;
  if (tid == 0) {
    float s = fmaxf(red[0], 1e-8f) / 127.0f;
    xscale[t] = s;
    ssh = s;
  }
  __syncthreads();
  const float s = ssh;
  unsigned* dst = (unsigned*)(xq + (size_t)t * 16384u);
#pragma unroll
  for (int i = 0; i < 16; ++i) {
    float4 v = vb[i];
    dst[(i << 8) + tid] = pack4i(qdiv(v.x, s), qdiv(v.y, s), qdiv(v.z, s), qdiv(v.w, s));
  }
}

// ---------------------------------------------------------------------------
// Persistent sequential kernel: 64 blocks x 512 threads.
__global__ __launch_bounds__(512, 2) void seq_kernel(
    const unsigned char* __restrict__ xq, const float* __restrict__ xscale,
    const unsigned char* __restrict__ wq_base, const unsigned* __restrict__ wmax,
    const float* __restrict__ bih0, const float* __restrict__ bhh0,
    const float* __restrict__ bih1, const float* __restrict__ bhh1,
    char* __restrict__ ws, const float* __restrict__ c0in, float* __restrict__ dout) {
  const int blk = blockIdx.x;
  const int layer = blk >> 5;
  const int lb = blk & 31;        // local block within layer
  const int j0 = lb << 5;         // 32 hidden units per block
  const int tid = threadIdx.x;
  const int w = tid >> 6;         // wave 0..7
  const int lane = tid & 63;
  const int g = w & 3;            // gate (i,f,g,o)
  const int ch = w >> 2;          // column half (0/1)

  unsigned* flags0 = (unsigned*)(ws + 128);
  unsigned* flags1 = (unsigned*)(ws + 256);
  unsigned* hmax0p = (unsigned*)(ws + 8192);
  unsigned* hmax1p = (unsigned*)(ws + 16384);
  float* h0f = (float*)(ws + 65536);
  float* h1f = (float*)(ws + 196608);
  unsigned char* h0qp = (unsigned char*)(ws + 327680);

  unsigned* myflags = layer ? flags1 : flags0;
  unsigned* myhmax = layer ? hmax1p : hmax0p;
  float* myhf = layer ? h1f : h0f;

  __shared__ __align__(16) unsigned char axq[16][1040];
  __shared__ __align__(16) unsigned char ahq[16][1040];
  __shared__ float gl[4][16][33];
  __shared__ float hstash[16][33];
  __shared__ float redw[8];

  const unsigned char* wqi = wq_base + (size_t)(2 * layer) * 4194304u;
  const unsigned char* wqh = wq_base + (size_t)(2 * layer + 1) * 4194304u;
  const float* bih = layer ? bih1 : bih0;
  const float* bhh = layer ? bhh1 : bhh0;
  const float s_wi = fmaxf(__uint_as_float(wmax[2 * layer + 0]), 1e-8f) / 127.0f;
  const float s_wh = fmaxf(__uint_as_float(wmax[2 * layer + 1]), 1e-8f) / 127.0f;

  // MFMA 16x16x64 i8 mapping (verified round 1):
  //   A: row=lane&15, k-offset=(lane>>4)*16;  D: col=lane&15, row=(lane>>4)*4+r
  const int ncol = (g << 10) + j0 + (ch << 4) + (lane & 15);
  const int ksub = (lane >> 4) << 4;
  const int arow = lane & 15;

  v4i wfi[16], wfh[16];
  {
    const unsigned char* pi = wqi + (size_t)ncol * 1024u + ksub;
    const unsigned char* ph = wqh + (size_t)ncol * 1024u + ksub;
#pragma unroll
    for (int kk = 0; kk < 16; ++kk) {
      wfi[kk] = *(const v4i*)(pi + (kk << 6));
      wfh[kk] = *(const v4i*)(ph + (kk << 6));
    }
  }
  const float bsum = bih[ncol] + bhh[ncol];

  const int cb = tid >> 5, cj = tid & 31;  // cell element (batch, unit)
  float creg = c0in[(layer << 14) + (cb << 10) + j0 + cj];

  if (layer == 0) {
    // ======================= LAYER 0: steps 0..1024 ========================
    for (int s = 0; s <= T_STEPS; ++s) {
      const bool full = (s < T_STEPS);
      v4i accx = {0, 0, 0, 0};
      if (full) {
        // x-side: static xq[s] (plain cached loads) — hoisted BEFORE the wait
        const v4i* src = (const v4i*)(xq + ((size_t)s << 14));
#pragma unroll
        for (int i = 0; i < 2; ++i) {
          int idx = (i << 9) + tid;
          v4i v = src[idx];
          int e = idx << 4;
          *(v4i*)&axq[e >> 10][e & 1023] = v;
        }
        __syncthreads();
#pragma unroll
        for (int kk = 0; kk < 16; ++kk) {
          v4i a = *(const v4i*)&axq[arow][(kk << 6) + ksub];
          accx = __builtin_amdgcn_mfma_i32_16x16x64_i8(a, wfi[kk], accx, 0, 0, 0);
        }
      }
      // wait: own recurrence (flags0 >= s) + h0q ring guard (flags1 >= s-8)
      const unsigned need1 = (s >= 8) ? (unsigned)(s - 8) : 0u;
      wait2(flags0, (unsigned)s, flags1, need1, tid);

      const float am = __uint_as_float(aload(&hmax0p[s]));
      const float sh = fmaxf(am, 1e-8f) / 127.0f;
      const float inv = 1.0f / sh;

      // publish h0q(s-1): producer-quantized int8 for layer1 (from hstash)
      if (s > 0 && tid < 128) {
        int f = tid << 2, b = f >> 5, c = f & 31;
        unsigned u = pack4i(qmul(hstash[b][c], inv), qmul(hstash[b][c + 1], inv),
                            qmul(hstash[b][c + 2], inv), qmul(hstash[b][c + 3], inv));
        cstore4(h0qp + ((size_t)((s - 1) & 7) << 14) + (b << 10) + j0 + c, u);
      }

      if (full) {
        // own-h: coherent read of f32 ring slot (s-1)&1, quantize, stage
        const char* hsrc = (const char*)(myhf + ((size_t)((s - 1) & 1) << 14));
        v4f hv[8];
#pragma unroll
        for (int i = 0; i < 8; ++i) {
          int idx = (i << 9) + tid;
          hv[i] = cloadf(hsrc + ((size_t)idx << 4));
        }
        vdone();
#pragma unroll
        for (int i = 0; i < 8; ++i) {
          unsigned u = pack4i(qmul(hv[i].x, inv), qmul(hv[i].y, inv),
                              qmul(hv[i].z, inv), qmul(hv[i].w, inv));
          int e = (i << 11) + (tid << 2);
          *(unsigned*)&ahq[e >> 10][e & 1023] = u;
        }
        __syncthreads();
        v4i acch = {0, 0, 0, 0};
#pragma unroll
        for (int kk = 0; kk < 16; ++kk) {
          v4i a = *(const v4i*)&ahq[arow][(kk << 6) + ksub];
          acch = __builtin_amdgcn_mfma_i32_16x16x64_i8(a, wfh[kk], acch, 0, 0, 0);
        }
        const float sx = xscale[s];
        const float fx = sx * s_wi, fh = sh * s_wh;
#pragma unroll
        for (int r = 0; r < 4; ++r) {
          float gate = (float)accx[r] * fx + (float)acch[r] * fh + bsum;
          float act = (g == 2) ? tanhf(gate) : 1.0f / (1.0f + expf(-gate));
          gl[g][((lane >> 4) << 2) + r][(ch << 4) + (lane & 15)] = act;
        }
        __syncthreads();
        float gi = gl[0][cb][cj], gf = gl[1][cb][cj];
        float gg = gl[2][cb][cj], go = gl[3][cb][cj];
        float cnew = gf * creg + gi * gg;
        creg = cnew;
        float h = go * tanhf(cnew);
        hstash[cb][cj] = h;
        float m = fabsf(h);
#pragma unroll
        for (int off = 32; off > 0; off >>= 1) m = fmaxf(m, __shfl_xor(m, off));
        if (lane == 0) redw[w] = m;
        if (s == T_STEPS - 1) dout[16777216u + (cb << 10) + j0 + cj] = h;
        __syncthreads();
        if (tid < 128) {  // f32 ring store (coherent), packed via hstash
          int f = tid << 2, b = f >> 5, c = f & 31;
          v4f hw = {hstash[b][c], hstash[b][c + 1], hstash[b][c + 2], hstash[b][c + 3]};
          cstore16(myhf + ((size_t)(s & 1) << 14) + (b << 10) + j0 + c, hw);
        }
        if (tid == 0) {
          float mm = redw[0];
#pragma unroll
          for (int i = 1; i < 8; ++i) mm = fmaxf(mm, redw[i]);
          amax(&hmax0p[s + 1], __float_as_uint(mm));
        }
      }
      vdone();
      __syncthreads();  // all waves' coherent stores acked
      if (tid == 0) astore(&flags0[lb], (unsigned)(s + 1));
    }
    dout[16777216u + 32768u + (cb << 10) + j0 + cj] = creg;
  } else {
    // ======================= LAYER 1: steps 0..1023 ========================
    for (int u = 0; u < T_STEPS; ++u) {
      // producer handshake: h0q(u) + hmax0[u+1] final once flags0 >= u+2
      wait2(flags0, (unsigned)(u + 2), nullptr, 0u, tid);
      const float sx = fmaxf(__uint_as_float(aload(&hmax0p[u + 1])), 1e-8f) / 127.0f;
      // x-side: coherent read of producer-quantized h0q slot u&7 (16 KB)
      {
        const char* qsrc = (const char*)h0qp + ((size_t)(u & 7) << 14);
        v4i q0 = cloadi(qsrc + ((size_t)tid << 4));
        v4i q1 = cloadi(qsrc + 8192 + ((size_t)tid << 4));
        vdone();
        int e0 = tid << 4;
        *(v4i*)&axq[e0 >> 10][e0 & 1023] = q0;
        int e1 = 8192 + (tid << 4);
        *(v4i*)&axq[e1 >> 10][e1 & 1023] = q1;
      }
      __syncthreads();
      v4i accx = {0, 0, 0, 0};
#pragma unroll
      for (int kk = 0; kk < 16; ++kk) {
        v4i a = *(const v4i*)&axq[arow][(kk << 6) + ksub];
        accx = __builtin_amdgcn_mfma_i32_16x16x64_i8(a, wfi[kk], accx, 0, 0, 0);
      }
      // own recurrence wait (x-work above overlapped this barrier's latency)
      wait2(flags1, (unsigned)u, nullptr, 0u, tid);
      const float sh = fmaxf(__uint_as_float(aload(&hmax1p[u])), 1e-8f) / 127.0f;
      const float inv = 1.0f / sh;
      const char* hsrc = (const char*)(myhf + ((size_t)((u - 1) & 1) << 14));
      v4f hv[8];
#pragma unroll
      for (int i = 0; i < 8; ++i) {
        int idx = (i << 9) + tid;
        hv[i] = cloadf(hsrc + ((size_t)idx << 4));
      }
      vdone();
#pragma unroll
      for (int i = 0; i < 8; ++i) {
        unsigned uq = pack4i(qmul(hv[i].x, inv), qmul(hv[i].y, inv),
                             qmul(hv[i].z, inv), qmul(hv[i].w, inv));
        int e = (i << 11) + (tid << 2);
        *(unsigned*)&ahq[e >> 10][e & 1023] = uq;
      }
      __syncthreads();
      v4i acch = {0, 0, 0, 0};
#pragma unroll
      for (int kk = 0; kk < 16; ++kk) {
        v4i a = *(const v4i*)&ahq[arow][(kk << 6) + ksub];
        acch = __builtin_amdgcn_mfma_i32_16x16x64_i8(a, wfh[kk], acch, 0, 0, 0);
      }
      const float fx = sx * s_wi, fh = sh * s_wh;
#pragma unroll
      for (int r = 0; r < 4; ++r) {
        float gate = (float)accx[r] * fx + (float)acch[r] * fh + bsum;
        float act = (g == 2) ? tanhf(gate) : 1.0f / (1.0f + expf(-gate));
        gl[g][((lane >> 4) << 2) + r][(ch << 4) + (lane & 15)] = act;
      }
      __syncthreads();
      float gi = gl[0][cb][cj], gf = gl[1][cb][cj];
      float gg = gl[2][cb][cj], go = gl[3][cb][cj];
      float cnew = gf * creg + gi * gg;
      creg = cnew;
      float h = go * tanhf(cnew);
      hstash[cb][cj] = h;
      float m = fabsf(h);
#pragma unroll
      for (int off = 32; off > 0; off >>= 1) m = fmaxf(m, __shfl_xor(m, off));
      if (lane == 0) redw[w] = m;
      dout[((size_t)u << 14) + (cb << 10) + j0 + cj] = h;  // y output (plain)
      if (u == T_STEPS - 1) dout[16777216u + 16384u + (cb << 10) + j0 + cj] = h;
      __syncthreads();
      if (tid < 128) {
        int f = tid << 2, b = f >> 5, c = f & 31;
        v4f hw = {hstash[b][c], hstash[b][c + 1], hstash[b][c + 2], hstash[b][c + 3]};
        cstore16(myhf + ((size_t)(u & 1) << 14) + (b << 10) + j0 + c, hw);
      }
      if (tid == 0) {
        float mm = redw[0];
#pragma unroll
        for (int i = 1; i < 8; ++i) mm = fmaxf(mm, redw[i]);
        amax(&hmax1p[u + 1], __float_as_uint(mm));
      }
      vdone();
      __syncthreads();
      if (tid == 0) astore(&flags1[lb], (unsigned)(u + 1));
    }
    dout[16777216u + 32768u + 16384u + (cb << 10) + j0 + cj] = creg;
  }
}

// ---------------------------------------------------------------------------
extern "C" void kernel_launch(void* const* d_in, const int* in_sizes, int n_in,
                              void* d_out, int out_size, void* d_ws, size_t ws_size,
                              hipStream_t stream) {
  (void)in_sizes; (void)n_in; (void)out_size; (void)ws_size;
  const float* x     = (const float*)d_in[0];
  const float* h0in  = (const float*)d_in[1];
  const float* c0in  = (const float*)d_in[2];
  const float* w_ih0 = (const float*)d_in[3];
  const float* w_hh0 = (const float*)d_in[4];
  const float* b_ih0 = (const float*)d_in[5];
  const float* b_hh0 = (const float*)d_in[6];
  const float* w_ih1 = (const float*)d_in[7];
  const float* w_hh1 = (const float*)d_in[8];
  const float* b_ih1 = (const float*)d_in[9];
  const float* b_hh1 = (const float*)d_in[10];

  char* ws = (char*)d_ws;
  unsigned* wmax   = (unsigned*)(ws + 0);
  float* xscale    = (float*)(ws + 1024);
  unsigned* hmax0  = (unsigned*)(ws + 8192);
  unsigned* hmax1  = (unsigned*)(ws + 16384);
  float* h0f       = (float*)(ws + 65536);
  float* h1f       = (float*)(ws + 196608);
  unsigned char* wqb = (unsigned char*)(ws + (1u << 20));
  unsigned char* xq  = (unsigned char*)(ws + (1u << 20) + 4u * 4194304u);

  hipMemsetAsync(ws, 0, 65536, stream);  // wmax, flags, hmax
  hipLaunchKernelGGL(init_kernel, dim3(2), dim3(256), 0, stream,
                     h0in, h0f, h1f, hmax0, hmax1);
  hipLaunchKernelGGL(wabsmax_kernel, dim3(1024), dim3(256), 0, stream,
                     w_ih0, w_hh0, w_ih1, w_hh1, wmax);
  hipLaunchKernelGGL(wquant_kernel, dim3(16384), dim3(256), 0, stream,
                     w_ih0, w_hh0, w_ih1, w_hh1, wmax, wqb);
  hipLaunchKernelGGL(xquant_kernel, dim3(1024), dim3(256), 0, stream,
                     x, xscale, xq);
  hipLaunchKernelGGL(seq_kernel, dim3(64), dim3(512), 0, stream,
                     xq, xscale, wqb, wmax,
                     b_ih0, b_hh0, b_ih1, b_hh1,
                     ws, c0in, (float*)d_out);
}